// Round 8
// baseline (276.715 us; speedup 1.0000x reference)
//
#include <hip/hip_runtime.h>
#include <hip/hip_bf16.h>
#include <math.h>

#define N_NODES 100000
#define N_EDGES 1600000
#define FDIM 166
#define HDIM 128
#define KP 192          // K padded to 6*32 (bf16 W layout)
#define CAP 64          // max in-degree slots; Poisson(16) => P(deg>64) ~ 1e-13
#define YTP 264         // LDS transpose pitch in ushorts (256 + 8 pad)
#define MBLK 64
#define XCHUNKS 42      // 16B chunks per staged row (672 B = 168 f32 >= 166)
#define XPITCH 672      // LDS row pitch in bytes
#define TOTCH (MBLK * XCHUNKS)       // 2688 chunks = 43008 B

typedef __attribute__((ext_vector_type(8))) short bf16x8;
typedef __attribute__((ext_vector_type(4))) float f32x4;

// global -> LDS direct DMA, 16B per lane; LDS dest must be wave-uniform base
#define GLOAD_LDS16(g, l) __builtin_amdgcn_global_load_lds( \
    (const __attribute__((address_space(1))) unsigned int*)(g), \
    (__attribute__((address_space(3))) unsigned int*)(l), 16, 0, 0)

// ---------- bf16 helpers (OCP bf16 = top 16 bits of f32) ----------
__device__ inline float bf2f(unsigned short s) {
    unsigned int u = ((unsigned int)s) << 16;
    float f; __builtin_memcpy(&f, &u, 4); return f;
}
__device__ inline float bflo(unsigned int u) {
    unsigned int v = u << 16;
    float f; __builtin_memcpy(&f, &v, 4); return f;
}
__device__ inline float bfhi(unsigned int u) {
    unsigned int v = u & 0xffff0000u;
    float f; __builtin_memcpy(&f, &v, 4); return f;
}
__device__ inline unsigned short f2bf(float f) {
    unsigned int u; __builtin_memcpy(&u, &f, 4);
    unsigned int r = u + 0x7fffu + ((u >> 16) & 1u);   // round-to-nearest-even
    return (unsigned short)(r >> 16);
}
// 8 f32 -> bf16x8 (RNE, emits v_cvt_pk_bf16_f32)
__device__ inline bf16x8 pack8(float4 a, float4 b) {
    union { bf16x8 v; __hip_bfloat162 h[4]; } u;
    u.h[0] = __float22bfloat162_rn(make_float2(a.x, a.y));
    u.h[1] = __float22bfloat162_rn(make_float2(a.z, a.w));
    u.h[2] = __float22bfloat162_rn(make_float2(b.x, b.y));
    u.h[3] = __float22bfloat162_rn(make_float2(b.z, b.w));
    return u.v;
}

// ---------- K_fill: R4-proven sequential counting fill (1 thread/edge) ----------
__global__ void k_fill(const int* __restrict__ ei, int* __restrict__ cnt,
                       int* __restrict__ adj) {
    int e = blockIdx.x * 256 + threadIdx.x;
    if (e >= N_EDGES) return;
    int s = ei[e];              // edge_index[0][e] = src
    int d = ei[N_EDGES + e];    // edge_index[1][e] = dst
    int slot = atomicAdd(&cnt[d], 1);
    if (slot < CAP) adj[d * CAP + slot] = s;
}

// ---------- K_prepw: pack W1l|W1r -> wt[256 cols][192 k] bf16 ----------
__global__ void k_prepw(const float* __restrict__ W1l, const float* __restrict__ W1r,
                        unsigned short* __restrict__ wt) {
    int idx = blockIdx.x * 256 + threadIdx.x;   // 256*192 total
    int c = idx / KP, k = idx - c * KP;
    float v = 0.f;
    if (k < FDIM)
        v = (c < HDIM) ? W1l[k * HDIM + c] : W1r[k * HDIM + (c - HDIM)];
    wt[idx] = f2bf(v);
}

// ---------- K_gemm: yl|yr = x @ [W1l|W1r], MFMA bf16 (R6-proven DMA staging) ----------
__global__ __launch_bounds__(256) void k_gemm(
        const float* __restrict__ x, const unsigned short* __restrict__ wt,
        unsigned short* __restrict__ yl, unsigned short* __restrict__ yr) {
    __shared__ __align__(16) char sm[43264];    // staging 43008+128 tail; epilogue 33792
    int tid = threadIdx.x;
    int r0 = blockIdx.x * MBLK;
    int w = tid >> 6, lane = tid & 63;

    // zero the row-63 fragment-overshoot tail [43008, 43136)
    if (tid < 32) *(float*)(sm + TOTCH * 16 + tid * 4) = 0.f;

    // ---- stage x tile -> LDS f32 [64][672B] via direct-to-LDS DMA ----
    {
        int wbase = w * 64;
        #pragma unroll
        for (int rd = 0; rd < 11; ++rd) {
            int base = rd * 256 + wbase;        // wave-uniform
            if (base < TOTCH) {
                int idx = base + lane;
                int row = idx / XCHUNKS, c = idx - row * XCHUNKS;
                int gr = r0 + row; if (gr > N_NODES - 1) gr = N_NODES - 1;
                const char* src = (const char*)x + (size_t)gr * (FDIM * 4) + c * 16;
                GLOAD_LDS16(src, sm + base * 16);
            }
        }
    }
    __syncthreads();

    int rbase = (w >> 1) * 32;          // wave rows (2 row-frags of 16)
    int c0 = (w & 1) * 128;             // wave cols (8 col-frags of 16)
    int l15 = lane & 15, g = lane >> 4;

    f32x4 acc[2][8];
    #pragma unroll
    for (int a = 0; a < 2; a++)
        #pragma unroll
        for (int b = 0; b < 8; b++) acc[a][b] = (f32x4){0.f, 0.f, 0.f, 0.f};

    const char* wb = (const char*)wt;
    int wlane = (c0 + l15) * (KP * 2) + 16 * g;     // A(W): col*384 + 16*g
    int brow0 = (rbase + l15) * XPITCH + 32 * g;    // B(x): f32 row base + k-group
    int brow1 = brow0 + 16 * XPITCH;

    bf16x8 ww[2][8];
    #pragma unroll
    for (int cf = 0; cf < 8; cf++)
        ww[0][cf] = *(const bf16x8*)(wb + wlane + cf * (16 * KP * 2));

    #pragma unroll
    for (int kk = 0; kk < 6; ++kk) {
        int cur = kk & 1, nxt = cur ^ 1;
        if (kk < 5) {
            #pragma unroll
            for (int cf = 0; cf < 8; cf++)
                ww[nxt][cf] = *(const bf16x8*)(wb + wlane + cf * (16 * KP * 2) + (kk + 1) * 64);
        }
        float4 p0 = *(const float4*)(sm + brow0 + kk * 128);
        float4 q0 = *(const float4*)(sm + brow0 + kk * 128 + 16);
        float4 p1 = *(const float4*)(sm + brow1 + kk * 128);
        float4 q1 = *(const float4*)(sm + brow1 + kk * 128 + 16);
        bf16x8 xb0 = pack8(p0, q0);
        bf16x8 xb1 = pack8(p1, q1);
        #pragma unroll
        for (int cf = 0; cf < 8; cf++) {
            acc[0][cf] = __builtin_amdgcn_mfma_f32_16x16x32_bf16(ww[cur][cf], xb0, acc[0][cf], 0, 0, 0);
            acc[1][cf] = __builtin_amdgcn_mfma_f32_16x16x32_bf16(ww[cur][cf], xb1, acc[1][cf], 0, 0, 0);
        }
    }
    __syncthreads();    // staging dead; reuse sm as yt[64][YTP] ushort

    // ---- acc -> LDS transpose (padded pitch; <=2-way bank alias = free) ----
    #pragma unroll
    for (int rf = 0; rf < 2; rf++) {
        int row = rbase + 16 * rf + l15;
        #pragma unroll
        for (int cf = 0; cf < 8; cf++) {
            int col = c0 + 16 * cf + 4 * g;
            ushort4 o;
            o.x = f2bf(acc[rf][cf][0]); o.y = f2bf(acc[rf][cf][1]);
            o.z = f2bf(acc[rf][cf][2]); o.w = f2bf(acc[rf][cf][3]);
            *(ushort4*)(sm + row * (YTP * 2) + col * 2) = o;
        }
    }
    __syncthreads();

    // ---- coalesced readback + 16B global stores (512B contiguous / half-wave) ----
    for (int it = 0; it < 8; ++it) {
        int n = tid + it * 256;
        int row = n >> 5, c16 = n & 31;
        uint4 v = *(const uint4*)(sm + row * (YTP * 2) + c16 * 16);
        int gr = r0 + row;
        if (gr < N_NODES) {
            unsigned short* dst = (c16 < 16) ? yl : yr;
            *(uint4*)((char*)dst + (size_t)gr * 256 + (size_t)(c16 & 15) * 16) = v;
        }
    }
}

// ---------- K_agg1: R4-proven — 1 wave/node, lane owns 2 features, 4-unroll ----------
__global__ __launch_bounds__(256) void k_agg1(
        const unsigned short* __restrict__ yl, const unsigned short* __restrict__ yr,
        const int* __restrict__ cnt, const int* __restrict__ adj,
        const float* __restrict__ b1,
        const float* __restrict__ W2l, const float* __restrict__ W2r,
        float* __restrict__ zw) {
    int w = threadIdx.x >> 6, lane = threadIdx.x & 63;
    int i = blockIdx.x * 4 + w;
    if (i >= N_NODES) return;
    int deg = cnt[i];
    int n = min(deg, CAP);
    int aidx = adj[i * CAP + lane];     // one coalesced 256B row load
    float a0 = 0.f, a1 = 0.f, p0 = 0.f, p1 = 0.f, q0 = 0.f, q1 = 0.f, r0 = 0.f, r1 = 0.f;
    int j = 0;
    for (; j + 4 <= n; j += 4) {
        int s0 = __shfl(aidx, j, 64);
        int s1 = __shfl(aidx, j + 1, 64);
        int s2 = __shfl(aidx, j + 2, 64);
        int s3 = __shfl(aidx, j + 3, 64);
        unsigned int u0 = *(const unsigned int*)&yl[(size_t)s0 * HDIM + lane * 2];
        unsigned int u1 = *(const unsigned int*)&yl[(size_t)s1 * HDIM + lane * 2];
        unsigned int u2 = *(const unsigned int*)&yl[(size_t)s2 * HDIM + lane * 2];
        unsigned int u3 = *(const unsigned int*)&yl[(size_t)s3 * HDIM + lane * 2];
        a0 += bflo(u0); a1 += bfhi(u0);
        p0 += bflo(u1); p1 += bfhi(u1);
        q0 += bflo(u2); q1 += bfhi(u2);
        r0 += bflo(u3); r1 += bfhi(u3);
    }
    for (; j < n; ++j) {
        int s = __shfl(aidx, j, 64);
        unsigned int u = *(const unsigned int*)&yl[(size_t)s * HDIM + lane * 2];
        a0 += bflo(u); a1 += bfhi(u);
    }
    a0 += p0 + q0 + r0;
    a1 += p1 + q1 + r1;
    float inv = 1.f / (float)max(deg, 1);
    unsigned int ur = *(const unsigned int*)&yr[(size_t)i * HDIM + lane * 2];
    float2 bb = *(const float2*)&b1[lane * 2];
    float h0 = fmaxf(a0 * inv + bflo(ur) + bb.x, 0.f);
    float h1 = fmaxf(a1 * inv + bfhi(ur) + bb.y, 0.f);
    float4 wl2 = *(const float4*)&W2l[lane * 4];   // rows 2lane,2lane+1 of [128][2]
    float4 wr2 = *(const float4*)&W2r[lane * 4];
    float z0 = h0 * wl2.x + h1 * wl2.z;
    float z1 = h0 * wl2.y + h1 * wl2.w;
    float w0 = h0 * wr2.x + h1 * wr2.z;
    float w1 = h0 * wr2.y + h1 * wr2.w;
    #pragma unroll
    for (int m = 32; m; m >>= 1) {
        z0 += __shfl_xor(z0, m, 64); z1 += __shfl_xor(z1, m, 64);
        w0 += __shfl_xor(w0, m, 64); w1 += __shfl_xor(w1, m, 64);
    }
    if (lane == 0) {
        float4 o = {z0, z1, w0, w1};
        *(float4*)&zw[i * 4] = o;
    }
}

// ---------- K_out: out = log_softmax(mean(z[nbrs]) + b2 + w) ----------
__global__ void k_out(const float* __restrict__ zw, const int* __restrict__ cnt,
                      const int* __restrict__ adj, const float* __restrict__ b2,
                      float* __restrict__ out) {
    int i = blockIdx.x * 256 + threadIdx.x;
    if (i >= N_NODES) return;
    int deg = cnt[i];
    int n = min(deg, CAP);
    float s0 = 0.f, s1 = 0.f;
    const int* arow = adj + i * CAP;
    for (int j = 0; j < n; j++) {
        int s = arow[j];
        float2 zz = *(const float2*)&zw[s * 4];
        s0 += zz.x; s1 += zz.y;
    }
    float inv = 1.f / (float)max(deg, 1);
    float p0 = s0 * inv + b2[0] + zw[i * 4 + 2];
    float p1 = s1 * inv + b2[1] + zw[i * 4 + 3];
    float mx = fmaxf(p0, p1);
    float lse = mx + logf(expf(p0 - mx) + expf(p1 - mx));
    out[i * 2 + 0] = p0 - lse;
    out[i * 2 + 1] = p1 - lse;
}

extern "C" void kernel_launch(void* const* d_in, const int* in_sizes, int n_in,
                              void* d_out, int out_size, void* d_ws, size_t ws_size,
                              hipStream_t stream) {
    const float* x   = (const float*)d_in[0];
    const int*   ei  = (const int*)d_in[1];
    const float* W1l = (const float*)d_in[2];
    const float* b1  = (const float*)d_in[3];
    const float* W1r = (const float*)d_in[4];
    const float* W2l = (const float*)d_in[5];
    const float* b2  = (const float*)d_in[6];
    const float* W2r = (const float*)d_in[7];
    float* out = (float*)d_out;

    char* ws = (char*)d_ws;
    size_t off = 0;
    auto alloc = [&](size_t bytes) {
        off = (off + 255) & ~(size_t)255;
        void* p = ws + off;
        off += bytes;
        return p;
    };
    int* cnt            = (int*)alloc((size_t)N_NODES * 4);
    int* adj            = (int*)alloc((size_t)N_NODES * CAP * 4);
    unsigned short* wt  = (unsigned short*)alloc((size_t)256 * KP * 2);
    unsigned short* yl  = (unsigned short*)alloc((size_t)N_NODES * HDIM * 2);
    unsigned short* yr  = (unsigned short*)alloc((size_t)N_NODES * HDIM * 2);
    float* zw           = (float*)alloc((size_t)N_NODES * 4 * 4);
    (void)ws_size; (void)in_sizes; (void)n_in; (void)out_size;

    hipMemsetAsync(cnt, 0, (size_t)N_NODES * 4, stream);
    k_fill<<<(N_EDGES + 255) / 256, 256, 0, stream>>>(ei, cnt, adj);
    k_prepw<<<(256 * KP) / 256, 256, 0, stream>>>(W1l, W1r, wt);
    k_gemm<<<(N_NODES + MBLK - 1) / MBLK, 256, 0, stream>>>(x, wt, yl, yr);
    k_agg1<<<(N_NODES + 3) / 4, 256, 0, stream>>>(yl, yr, cnt, adj, b1, W2l, W2r, zw);
    k_out<<<(N_NODES + 255) / 256, 256, 0, stream>>>(zw, cnt, adj, b2, out);
}

// Round 9
// 223.606 us; speedup vs baseline: 1.2375x; 1.2375x over previous
//
#include <hip/hip_runtime.h>
#include <hip/hip_bf16.h>
#include <math.h>

#define N_NODES 100000
#define N_EDGES 1600000
#define FDIM 166
#define HDIM 128
#define KP 192          // K padded to 6*32 (bf16 W layout)
#define CAP 64          // max in-degree slots; Poisson(16) => P(deg>64) ~ 1e-13
#define YTP 264         // LDS transpose pitch in ushorts (256 + 8 pad)
#define MBLK 64
#define XCHUNKS 42      // 16B chunks per staged row (672 B = 168 f32 >= 166)
#define XPITCH 672      // LDS row pitch in bytes
#define TOTCH (MBLK * XCHUNKS)       // 2688 chunks = 43008 B
#define NXCD 8
#define NODES_PER (N_NODES / NXCD)   // 12500

typedef __attribute__((ext_vector_type(8))) short bf16x8;
typedef __attribute__((ext_vector_type(4))) float f32x4;

// global -> LDS direct DMA, 16B per lane; LDS dest must be wave-uniform base
#define GLOAD_LDS16(g, l) __builtin_amdgcn_global_load_lds( \
    (const __attribute__((address_space(1))) unsigned int*)(g), \
    (__attribute__((address_space(3))) unsigned int*)(l), 16, 0, 0)

// ---------- bf16 helpers (OCP bf16 = top 16 bits of f32) ----------
__device__ inline float bf2f(unsigned short s) {
    unsigned int u = ((unsigned int)s) << 16;
    float f; __builtin_memcpy(&f, &u, 4); return f;
}
__device__ inline float bflo(unsigned int u) {
    unsigned int v = u << 16;
    float f; __builtin_memcpy(&f, &v, 4); return f;
}
__device__ inline float bfhi(unsigned int u) {
    unsigned int v = u & 0xffff0000u;
    float f; __builtin_memcpy(&f, &v, 4); return f;
}
__device__ inline unsigned short f2bf(float f) {
    unsigned int u; __builtin_memcpy(&u, &f, 4);
    unsigned int r = u + 0x7fffu + ((u >> 16) & 1u);   // round-to-nearest-even
    return (unsigned short)(r >> 16);
}
// 8 f32 -> bf16x8 (RNE, emits v_cvt_pk_bf16_f32)
__device__ inline bf16x8 pack8(float4 a, float4 b) {
    union { bf16x8 v; __hip_bfloat162 h[4]; } u;
    u.h[0] = __float22bfloat162_rn(make_float2(a.x, a.y));
    u.h[1] = __float22bfloat162_rn(make_float2(a.z, a.w));
    u.h[2] = __float22bfloat162_rn(make_float2(b.x, b.y));
    u.h[3] = __float22bfloat162_rn(make_float2(b.z, b.w));
    return u.v;
}

// ---------- K_fill: XCD-sharded counting fill, PLAIN loads (no nontemporal) ----------
// shard xcd owns dst range [xcd*12500, +12500): adj slice (3.2MB) + cnt slice
// stay mostly L2-resident per XCD. NT loads removed: suspected stale-DRAM reads
// (every elevated-absmax round used NT; every plain-load round was bit-stable).
__global__ __launch_bounds__(256) void k_fill(const int* __restrict__ ei,
                                              int* __restrict__ cnt,
                                              int* __restrict__ adj) {
    int xcd = blockIdx.x & (NXCD - 1);
    int grp = blockIdx.x >> 3;
    int lo = xcd * NODES_PER, hi = lo + NODES_PER;
    int stride = (gridDim.x >> 3) * 256;
    for (int e = grp * 256 + threadIdx.x; e < N_EDGES; e += stride) {
        int d = ei[N_EDGES + e];
        if (d >= lo && d < hi) {
            int s = ei[e];
            int slot = atomicAdd(&cnt[d], 1);
            if (slot < CAP) adj[d * CAP + slot] = s;
        }
    }
}

// ---------- K_prepw: pack W1l|W1r -> wt[256 cols][192 k] bf16 ----------
__global__ void k_prepw(const float* __restrict__ W1l, const float* __restrict__ W1r,
                        unsigned short* __restrict__ wt) {
    int idx = blockIdx.x * 256 + threadIdx.x;   // 256*192 total
    int c = idx / KP, k = idx - c * KP;
    float v = 0.f;
    if (k < FDIM)
        v = (c < HDIM) ? W1l[k * HDIM + c] : W1r[k * HDIM + (c - HDIM)];
    wt[idx] = f2bf(v);
}

// ---------- K_gemm: yl|yr = x @ [W1l|W1r], MFMA bf16 (R8-proven DMA staging) ----------
__global__ __launch_bounds__(256) void k_gemm(
        const float* __restrict__ x, const unsigned short* __restrict__ wt,
        unsigned short* __restrict__ yl, unsigned short* __restrict__ yr) {
    __shared__ __align__(16) char sm[43264];    // staging 43008+128 tail; epilogue 33792
    int tid = threadIdx.x;
    int r0 = blockIdx.x * MBLK;
    int w = tid >> 6, lane = tid & 63;

    // zero the row-63 fragment-overshoot tail [43008, 43136)
    if (tid < 32) *(float*)(sm + TOTCH * 16 + tid * 4) = 0.f;

    // ---- stage x tile -> LDS f32 [64][672B] via direct-to-LDS DMA ----
    {
        int wbase = w * 64;
        #pragma unroll
        for (int rd = 0; rd < 11; ++rd) {
            int base = rd * 256 + wbase;        // wave-uniform
            if (base < TOTCH) {
                int idx = base + lane;
                int row = idx / XCHUNKS, c = idx - row * XCHUNKS;
                int gr = r0 + row; if (gr > N_NODES - 1) gr = N_NODES - 1;
                const char* src = (const char*)x + (size_t)gr * (FDIM * 4) + c * 16;
                GLOAD_LDS16(src, sm + base * 16);
            }
        }
    }
    __syncthreads();

    int rbase = (w >> 1) * 32;          // wave rows (2 row-frags of 16)
    int c0 = (w & 1) * 128;             // wave cols (8 col-frags of 16)
    int l15 = lane & 15, g = lane >> 4;

    f32x4 acc[2][8];
    #pragma unroll
    for (int a = 0; a < 2; a++)
        #pragma unroll
        for (int b = 0; b < 8; b++) acc[a][b] = (f32x4){0.f, 0.f, 0.f, 0.f};

    const char* wb = (const char*)wt;
    int wlane = (c0 + l15) * (KP * 2) + 16 * g;     // A(W): col*384 + 16*g
    int brow0 = (rbase + l15) * XPITCH + 32 * g;    // B(x): f32 row base + k-group
    int brow1 = brow0 + 16 * XPITCH;

    bf16x8 ww[2][8];
    #pragma unroll
    for (int cf = 0; cf < 8; cf++)
        ww[0][cf] = *(const bf16x8*)(wb + wlane + cf * (16 * KP * 2));

    #pragma unroll
    for (int kk = 0; kk < 6; ++kk) {
        int cur = kk & 1, nxt = cur ^ 1;
        if (kk < 5) {
            #pragma unroll
            for (int cf = 0; cf < 8; cf++)
                ww[nxt][cf] = *(const bf16x8*)(wb + wlane + cf * (16 * KP * 2) + (kk + 1) * 64);
        }
        float4 p0 = *(const float4*)(sm + brow0 + kk * 128);
        float4 q0 = *(const float4*)(sm + brow0 + kk * 128 + 16);
        float4 p1 = *(const float4*)(sm + brow1 + kk * 128);
        float4 q1 = *(const float4*)(sm + brow1 + kk * 128 + 16);
        bf16x8 xb0 = pack8(p0, q0);
        bf16x8 xb1 = pack8(p1, q1);
        #pragma unroll
        for (int cf = 0; cf < 8; cf++) {
            acc[0][cf] = __builtin_amdgcn_mfma_f32_16x16x32_bf16(ww[cur][cf], xb0, acc[0][cf], 0, 0, 0);
            acc[1][cf] = __builtin_amdgcn_mfma_f32_16x16x32_bf16(ww[cur][cf], xb1, acc[1][cf], 0, 0, 0);
        }
    }
    __syncthreads();    // staging dead; reuse sm as yt[64][YTP] ushort

    // ---- acc -> LDS transpose (padded pitch; <=2-way bank alias = free) ----
    #pragma unroll
    for (int rf = 0; rf < 2; rf++) {
        int row = rbase + 16 * rf + l15;
        #pragma unroll
        for (int cf = 0; cf < 8; cf++) {
            int col = c0 + 16 * cf + 4 * g;
            ushort4 o;
            o.x = f2bf(acc[rf][cf][0]); o.y = f2bf(acc[rf][cf][1]);
            o.z = f2bf(acc[rf][cf][2]); o.w = f2bf(acc[rf][cf][3]);
            *(ushort4*)(sm + row * (YTP * 2) + col * 2) = o;
        }
    }
    __syncthreads();

    // ---- coalesced readback + 16B global stores (512B contiguous / half-wave) ----
    for (int it = 0; it < 8; ++it) {
        int n = tid + it * 256;
        int row = n >> 5, c16 = n & 31;
        uint4 v = *(const uint4*)(sm + row * (YTP * 2) + c16 * 16);
        int gr = r0 + row;
        if (gr < N_NODES) {
            unsigned short* dst = (c16 < 16) ? yl : yr;
            *(uint4*)((char*)dst + (size_t)gr * 256 + (size_t)(c16 & 15) * 16) = v;
        }
    }
}

// ---------- K_agg1: R8-proven — 1 wave/node, lane owns 2 features, 4-unroll ----------
__global__ __launch_bounds__(256) void k_agg1(
        const unsigned short* __restrict__ yl, const unsigned short* __restrict__ yr,
        const int* __restrict__ cnt, const int* __restrict__ adj,
        const float* __restrict__ b1,
        const float* __restrict__ W2l, const float* __restrict__ W2r,
        float* __restrict__ zw) {
    int w = threadIdx.x >> 6, lane = threadIdx.x & 63;
    int i = blockIdx.x * 4 + w;
    if (i >= N_NODES) return;
    int deg = cnt[i];
    int n = min(deg, CAP);
    int aidx = adj[i * CAP + lane];     // one coalesced 256B row load
    float a0 = 0.f, a1 = 0.f, p0 = 0.f, p1 = 0.f, q0 = 0.f, q1 = 0.f, r0 = 0.f, r1 = 0.f;
    int j = 0;
    for (; j + 4 <= n; j += 4) {
        int s0 = __shfl(aidx, j, 64);
        int s1 = __shfl(aidx, j + 1, 64);
        int s2 = __shfl(aidx, j + 2, 64);
        int s3 = __shfl(aidx, j + 3, 64);
        unsigned int u0 = *(const unsigned int*)&yl[(size_t)s0 * HDIM + lane * 2];
        unsigned int u1 = *(const unsigned int*)&yl[(size_t)s1 * HDIM + lane * 2];
        unsigned int u2 = *(const unsigned int*)&yl[(size_t)s2 * HDIM + lane * 2];
        unsigned int u3 = *(const unsigned int*)&yl[(size_t)s3 * HDIM + lane * 2];
        a0 += bflo(u0); a1 += bfhi(u0);
        p0 += bflo(u1); p1 += bfhi(u1);
        q0 += bflo(u2); q1 += bfhi(u2);
        r0 += bflo(u3); r1 += bfhi(u3);
    }
    for (; j < n; ++j) {
        int s = __shfl(aidx, j, 64);
        unsigned int u = *(const unsigned int*)&yl[(size_t)s * HDIM + lane * 2];
        a0 += bflo(u); a1 += bfhi(u);
    }
    a0 += p0 + q0 + r0;
    a1 += p1 + q1 + r1;
    float inv = 1.f / (float)max(deg, 1);
    unsigned int ur = *(const unsigned int*)&yr[(size_t)i * HDIM + lane * 2];
    float2 bb = *(const float2*)&b1[lane * 2];
    float h0 = fmaxf(a0 * inv + bflo(ur) + bb.x, 0.f);
    float h1 = fmaxf(a1 * inv + bfhi(ur) + bb.y, 0.f);
    float4 wl2 = *(const float4*)&W2l[lane * 4];   // rows 2lane,2lane+1 of [128][2]
    float4 wr2 = *(const float4*)&W2r[lane * 4];
    float z0 = h0 * wl2.x + h1 * wl2.z;
    float z1 = h0 * wl2.y + h1 * wl2.w;
    float w0 = h0 * wr2.x + h1 * wr2.z;
    float w1 = h0 * wr2.y + h1 * wr2.w;
    #pragma unroll
    for (int m = 32; m; m >>= 1) {
        z0 += __shfl_xor(z0, m, 64); z1 += __shfl_xor(z1, m, 64);
        w0 += __shfl_xor(w0, m, 64); w1 += __shfl_xor(w1, m, 64);
    }
    if (lane == 0) {
        float4 o = {z0, z1, w0, w1};
        *(float4*)&zw[i * 4] = o;
    }
}

// ---------- K_out: out = log_softmax(mean(z[nbrs]) + b2 + w) ----------
__global__ void k_out(const float* __restrict__ zw, const int* __restrict__ cnt,
                      const int* __restrict__ adj, const float* __restrict__ b2,
                      float* __restrict__ out) {
    int i = blockIdx.x * 256 + threadIdx.x;
    if (i >= N_NODES) return;
    int deg = cnt[i];
    int n = min(deg, CAP);
    float s0 = 0.f, s1 = 0.f;
    const int* arow = adj + i * CAP;
    for (int j = 0; j < n; j++) {
        int s = arow[j];
        float2 zz = *(const float2*)&zw[s * 4];
        s0 += zz.x; s1 += zz.y;
    }
    float inv = 1.f / (float)max(deg, 1);
    float p0 = s0 * inv + b2[0] + zw[i * 4 + 2];
    float p1 = s1 * inv + b2[1] + zw[i * 4 + 3];
    float mx = fmaxf(p0, p1);
    float lse = mx + logf(expf(p0 - mx) + expf(p1 - mx));
    out[i * 2 + 0] = p0 - lse;
    out[i * 2 + 1] = p1 - lse;
}

extern "C" void kernel_launch(void* const* d_in, const int* in_sizes, int n_in,
                              void* d_out, int out_size, void* d_ws, size_t ws_size,
                              hipStream_t stream) {
    const float* x   = (const float*)d_in[0];
    const int*   ei  = (const int*)d_in[1];
    const float* W1l = (const float*)d_in[2];
    const float* b1  = (const float*)d_in[3];
    const float* W1r = (const float*)d_in[4];
    const float* W2l = (const float*)d_in[5];
    const float* b2  = (const float*)d_in[6];
    const float* W2r = (const float*)d_in[7];
    float* out = (float*)d_out;

    char* ws = (char*)d_ws;
    size_t off = 0;
    auto alloc = [&](size_t bytes) {
        off = (off + 255) & ~(size_t)255;
        void* p = ws + off;
        off += bytes;
        return p;
    };
    int* cnt            = (int*)alloc((size_t)N_NODES * 4);
    int* adj            = (int*)alloc((size_t)N_NODES * CAP * 4);
    unsigned short* wt  = (unsigned short*)alloc((size_t)256 * KP * 2);
    unsigned short* yl  = (unsigned short*)alloc((size_t)N_NODES * HDIM * 2);
    unsigned short* yr  = (unsigned short*)alloc((size_t)N_NODES * HDIM * 2);
    float* zw           = (float*)alloc((size_t)N_NODES * 4 * 4);
    (void)ws_size; (void)in_sizes; (void)n_in; (void)out_size;

    hipMemsetAsync(cnt, 0, (size_t)N_NODES * 4, stream);
    k_fill<<<2048, 256, 0, stream>>>(ei, cnt, adj);
    k_prepw<<<(256 * KP) / 256, 256, 0, stream>>>(W1l, W1r, wt);
    k_gemm<<<(N_NODES + MBLK - 1) / MBLK, 256, 0, stream>>>(x, wt, yl, yr);
    k_agg1<<<(N_NODES + 3) / 4, 256, 0, stream>>>(yl, yr, cnt, adj, b1, W2l, W2r, zw);
    k_out<<<(N_NODES + 255) / 256, 256, 0, stream>>>(zw, cnt, adj, b2, out);
}